// Round 5
// baseline (345.828 us; speedup 1.0000x reference)
//
#include <hip/hip_runtime.h>
#include <math.h>

#ifndef M_PI
#define M_PI 3.14159265358979323846
#endif

#define T_ROWS 1024
#define EDIM   2048
#define IN_DIM 1024
#define OUT_DIM 1024
#define NMODES 16
#define NLAYERS 4

typedef __attribute__((ext_vector_type(8))) short bf16x8;
typedef __attribute__((ext_vector_type(4))) float f32x4;

__device__ __forceinline__ unsigned short f2bf(float f) {
  union { float f; unsigned u; } v; v.f = f;
  unsigned r = v.u + 0x7FFFu + ((v.u >> 16) & 1u);  // RNE
  return (unsigned short)(r >> 16);
}
__device__ __forceinline__ float bf2f(unsigned short h) {
  union { unsigned u; float f; } v; v.u = ((unsigned)h) << 16;
  return v.f;
}
__device__ __forceinline__ void f2bf_split(float v, unsigned short& h, unsigned short& l) {
  h = f2bf(v);
  l = f2bf(v - bf2f(h));
}

__device__ __forceinline__ float gelu_fast(float x) {
  float x2 = x * x;
  float inner = x * (0.7978845608028654f + 0.0356774081f * x2);
  float e2 = __builtin_amdgcn_exp2f(inner * 2.885390081777927f);
  float r  = __builtin_amdgcn_rcpf(e2 + 1.0f);
  return 0.5f * x * (2.0f - 2.0f * r);
}

// Fused setup.
// blocks 0..7: ctab/stab; 8..263: basF hi/lo fragment table [128 mt][64 lane][8 i]
//   x = mt*16 + (lane&15), j = (lane>>4)*8 + i; j<16: cos(2pi j x/2048),
//   16<=j<31: sin(2pi (j-15) x/2048), j==31: 0
// block 264: folded layer weights
__global__ __launch_bounds__(256)
void setup_all(float* __restrict__ ctab, float* __restrict__ stab,
               unsigned short* __restrict__ basFh, unsigned short* __restrict__ basFl,
               const float* __restrict__ fc0w, const float* __restrict__ fc0b,
               const float* __restrict__ wr, const float* __restrict__ wi,
               const float* __restrict__ pww, const float* __restrict__ pwb,
               float* __restrict__ Wmr, float* __restrict__ Wmi,
               float* __restrict__ b0r, float* __restrict__ pw1,
               float* __restrict__ pb1)
{
  const int b = blockIdx.x, tid = threadIdx.x;
  if (b < 8) {
    int i = b * 256 + tid;
    double ang = (2.0 * M_PI / (double)EDIM) * (double)i;
    ctab[i] = (float)cos(ang);
    stab[i] = (float)sin(ang);
  } else if (b < 264) {
    int idx = (b - 8) * 256 + tid;            // [0, 65536)
    int mt = idx >> 9;
    int l  = (idx >> 3) & 63;
    int i  = idx & 7;
    int x  = mt * 16 + (l & 15);
    int j  = (l >> 4) * 8 + i;
    float v = 0.0f;
    if (j < 31) {
      int m = (j < NMODES) ? j : (j - 15);
      int ia = (m * x) & (EDIM - 1);
      double ang = (2.0 * M_PI / (double)EDIM) * (double)ia;
      v = (j < NMODES) ? (float)cos(ang) : (float)sin(ang);
    }
    unsigned short h, lo; f2bf_split(v, h, lo);
    basFh[idx] = h; basFl[idx] = lo;
  } else {
    if (tid >= NLAYERS * 32) return;
    int l = tid >> 5, d = tid & 31;
    for (int m = 0; m < NMODES; ++m) {
      float sr = 0.f, si = 0.f;
      for (int c = 0; c < 32; ++c) {
        float w0 = fc0w[l * 32 + c];
        size_t base = ((size_t)(l * 32 + c) * 32 + d) * NMODES + m;
        sr += w0 * wr[base];
        si += w0 * wi[base];
      }
      Wmr[(l * NMODES + m) * 32 + d] = sr;
      Wmi[(l * NMODES + m) * 32 + d] = si;
    }
    float sb = 0.f, sp = 0.f, sq = 0.f;
    for (int c = 0; c < 32; ++c) {
      float b0 = fc0b[l * 32 + c];
      float w0 = fc0w[l * 32 + c];
      sb += b0 * wr[((size_t)(l * 32 + c) * 32 + d) * NMODES + 0];
      float pw = pww[(size_t)(l * 32 + c) * 32 + d];
      sp += w0 * pw;
      sq += b0 * pw;
    }
    b0r[l * 32 + d] = (float)EDIM * sb;
    pw1[l * 32 + d] = sp;
    pb1[l * 32 + d] = sq + pwb[l * 32 + d];
  }
}

// B[K][N] fp32 -> BT[N][K] bf16, 32x32 tiles
__global__ __launch_bounds__(256)
void transpose_cvt(const float* __restrict__ B, unsigned short* __restrict__ BT,
                   int K, int N)
{
  __shared__ float tile[32][33];
  const int k0 = blockIdx.y * 32, n0 = blockIdx.x * 32;
  const int tid = threadIdx.x;
  {
    int r = tid >> 3, c4 = (tid & 7) * 4;
    float4 v = *(const float4*)&B[(size_t)(k0 + r) * N + n0 + c4];
    tile[r][c4 + 0] = v.x; tile[r][c4 + 1] = v.y;
    tile[r][c4 + 2] = v.z; tile[r][c4 + 3] = v.w;
  }
  __syncthreads();
  {
    int n = tid >> 3, kq = (tid & 7) * 4;
    ushort4 o;
    o.x = f2bf(tile[kq + 0][n]); o.y = f2bf(tile[kq + 1][n]);
    o.z = f2bf(tile[kq + 2][n]); o.w = f2bf(tile[kq + 3][n]);
    *(ushort4*)&BT[(size_t)(n0 + n) * K + k0 + kq] = o;
  }
}

// C[M][N] = A[M][K](fp32 -> bf16 on stage) @ BT[N][K]^T + bias. 64x64 tile, BK=64.
#define BKK 64
__global__ __launch_bounds__(256)
void gemm_mfma(const float* __restrict__ A, const unsigned short* __restrict__ BT,
               const float* __restrict__ bias, float* __restrict__ C,
               int M, int N, int K)
{
  __shared__ __align__(16) unsigned short Asb[64 * BKK];
  __shared__ __align__(16) unsigned short Bsb[64 * BKK];
  const int tid = threadIdx.x;
  const int bm = blockIdx.y * 64, bn = blockIdx.x * 64;
  const int lane = tid & 63, wave = tid >> 6;
  const int wr = wave >> 1, wc = wave & 1;

  const int srow = tid >> 2;          // 0..63
  const int skq  = tid & 3;           // 16-k chunk

  f32x4 acc[2][2] = {};

  const float* aRow = A + (size_t)(bm + srow) * K + skq * 16;
  const unsigned short* bRow = BT + (size_t)(bn + srow) * K + skq * 16;

  for (int k0 = 0; k0 < K; k0 += BKK) {
    #pragma unroll
    for (int h = 0; h < 2; ++h) {
      int kb = skq * 2 + h;
      int slot = kb ^ ((srow >> 1) & 7);
      {
        float4 a0 = *(const float4*)(aRow + k0 + h * 8);
        float4 a1 = *(const float4*)(aRow + k0 + h * 8 + 4);
        union { unsigned short u[8]; bf16x8 v; } pk;
        pk.u[0] = f2bf(a0.x); pk.u[1] = f2bf(a0.y); pk.u[2] = f2bf(a0.z); pk.u[3] = f2bf(a0.w);
        pk.u[4] = f2bf(a1.x); pk.u[5] = f2bf(a1.y); pk.u[6] = f2bf(a1.z); pk.u[7] = f2bf(a1.w);
        *(bf16x8*)&Asb[srow * BKK + slot * 8] = pk.v;
      }
      *(bf16x8*)&Bsb[srow * BKK + slot * 8] = *(const bf16x8*)(bRow + k0 + h * 8);
    }
    __syncthreads();
    #pragma unroll
    for (int s = 0; s < 2; ++s) {
      int kb = s * 4 + (lane >> 4);
      bf16x8 a[2], b[2];
      #pragma unroll
      for (int i = 0; i < 2; ++i) {
        int ar = wr * 32 + i * 16 + (lane & 15);
        a[i] = *(const bf16x8*)&Asb[ar * BKK + (kb ^ ((ar >> 1) & 7)) * 8];
        int br = wc * 32 + i * 16 + (lane & 15);
        b[i] = *(const bf16x8*)&Bsb[br * BKK + (kb ^ ((br >> 1) & 7)) * 8];
      }
      #pragma unroll
      for (int i = 0; i < 2; ++i)
        #pragma unroll
        for (int j = 0; j < 2; ++j)
          acc[i][j] = __builtin_amdgcn_mfma_f32_16x16x32_bf16(a[i], b[j], acc[i][j], 0, 0, 0);
    }
    __syncthreads();
  }

  #pragma unroll
  for (int j = 0; j < 2; ++j) {
    int col = bn + wc * 32 + j * 16 + (lane & 15);
    float bz = bias[col];
    #pragma unroll
    for (int i = 0; i < 2; ++i)
      #pragma unroll
      for (int r = 0; r < 4; ++r) {
        int row = bm + wr * 32 + i * 16 + (lane >> 4) * 4 + r;
        C[(size_t)row * N + col] = acc[i][j][r] + bz;
      }
  }
}

// 16-mode DFT per row + mode mix -> bf16 hi/lo fragments coefF[t][n][lane][8]
// (A-frag order when coef is the M=d operand: row d = n*16+(lane&15), k j=(lane>>4)*8+i)
__global__ __launch_bounds__(256)
void dft_coef(const float* __restrict__ u,
              const float* __restrict__ ctab, const float* __restrict__ stab,
              const float* __restrict__ Wmr, const float* __restrict__ Wmi,
              const float* __restrict__ b0r,
              unsigned short* __restrict__ coefFh, unsigned short* __restrict__ coefFl)
{
  const int t = blockIdx.x, tid = threadIdx.x;
  __shared__ float lc[EDIM + 64], ls[EDIM + 64];
  __shared__ float red[4][32];
  __shared__ float Ush[32];

  for (int i = tid; i < EDIM; i += 256) {
    int p = i + (i >> 5);
    lc[p] = ctab[i];
    ls[p] = stab[i];
  }
  float ur[8];
  #pragma unroll
  for (int it = 0; it < 8; ++it) ur[it] = u[(size_t)t * EDIM + tid + it * 256];
  __syncthreads();

  float pr[NMODES], pi[NMODES];
  #pragma unroll
  for (int m = 0; m < NMODES; ++m) { pr[m] = 0.f; pi[m] = 0.f; }
  #pragma unroll
  for (int it = 0; it < 8; ++it) {
    int x = tid + it * 256;
    float val = ur[it];
    #pragma unroll
    for (int m = 0; m < NMODES; ++m) {
      int idx = (m * x) & (EDIM - 1);
      int p = idx + (idx >> 5);
      pr[m] += val * lc[p];
      pi[m] -= val * ls[p];
    }
  }
  #pragma unroll
  for (int m = 0; m < NMODES; ++m) {
    #pragma unroll
    for (int off = 32; off > 0; off >>= 1) {
      pr[m] += __shfl_down(pr[m], off, 64);
      pi[m] += __shfl_down(pi[m], off, 64);
    }
  }
  int lane = tid & 63, wid = tid >> 6;
  if (lane == 0) {
    #pragma unroll
    for (int m = 0; m < NMODES; ++m) { red[wid][m] = pr[m]; red[wid][NMODES + m] = pi[m]; }
  }
  __syncthreads();
  if (tid < 32) Ush[tid] = red[0][tid] + red[1][tid] + red[2][tid] + red[3][tid];
  __syncthreads();

  if (tid < 128) {
    const float invN = 1.0f / (float)EDIM;
    int n = tid >> 6, l = tid & 63;
    int d = n * 16 + (l & 15);
    union { unsigned short u[8]; bf16x8 v; } ph, pl;
    #pragma unroll
    for (int i = 0; i < 8; ++i) {
      int j = (l >> 4) * 8 + i;
      float v = 0.f;
      if (j < 31) {
        if (j < NMODES) {
          int m = j;
          float ofr = Ush[m] * Wmr[m * 32 + d] - Ush[NMODES + m] * Wmi[m * 32 + d];
          v = (m == 0) ? (ofr + b0r[d]) * invN : 2.0f * ofr * invN;
        } else {
          int m = j - 15;
          float ofi = Ush[m] * Wmi[m * 32 + d] + Ush[NMODES + m] * Wmr[m * 32 + d];
          v = -2.0f * ofi * invN;
        }
      }
      f2bf_split(v, ph.u[i], pl.u[i]);
    }
    size_t base = ((size_t)t * 2 + n) * 64 + l;
    *(bf16x8*)&coefFh[base * 8] = ph.v;
    *(bf16x8*)&coefFl[base * 8] = pl.v;
  }
}

// MFMA reconstruction + gelu + fc1, in-place on u. One block = 2 t-rows.
// Operand-swapped: C[row=d][col=x] = coef^T... i.e. mfma(A=coef, B=bas).
// Epilogue fully in registers: per-lane d-slice, fc1 reduce = 2x shfl_xor.
__global__ __launch_bounds__(256)
void recon_mfma(float* __restrict__ u,
                const unsigned short* __restrict__ basFh,
                const unsigned short* __restrict__ basFl,
                const unsigned short* __restrict__ coefFh,
                const unsigned short* __restrict__ coefFl,
                const float* __restrict__ pw1, const float* __restrict__ pb1,
                const float* __restrict__ f1w, const float* __restrict__ f1b)
{
  const int t0 = blockIdx.x * 2;
  const int tid = threadIdx.x, lane = tid & 63, w = tid >> 6;
  const int g = lane >> 4, m15 = lane & 15;

  bf16x8 ch[2][2], cl[2][2];
  #pragma unroll
  for (int tt = 0; tt < 2; ++tt)
    #pragma unroll
    for (int n = 0; n < 2; ++n) {
      size_t base = (((size_t)(t0 + tt) * 2 + n) * 64 + lane) * 8;
      ch[tt][n] = *(const bf16x8*)&coefFh[base];
      cl[tt][n] = *(const bf16x8*)&coefFl[base];
    }

  // per-lane epilogue constants: d = n*16 + g*4 + r  (contiguous float4 at g*4)
  float4 pwv[2], pbv[2], fv[2];
  #pragma unroll
  for (int n = 0; n < 2; ++n) {
    pwv[n] = *(const float4*)&pw1[n * 16 + g * 4];
    pbv[n] = *(const float4*)&pb1[n * 16 + g * 4];
    fv[n]  = *(const float4*)&f1w[n * 16 + g * 4];
  }
  const float fb = f1b[0];

  for (int c = 0; c < 8; ++c) {
    f32x4 acc[4][2][2];
    #pragma unroll
    for (int q = 0; q < 4; ++q) {
      const int mt = w * 32 + c * 4 + q;
      bf16x8 bh = *(const bf16x8*)&basFh[((size_t)mt * 64 + lane) * 8];
      bf16x8 bl = *(const bf16x8*)&basFl[((size_t)mt * 64 + lane) * 8];
      #pragma unroll
      for (int tt = 0; tt < 2; ++tt)
        #pragma unroll
        for (int n = 0; n < 2; ++n) {
          f32x4 a = {};
          a = __builtin_amdgcn_mfma_f32_16x16x32_bf16(cl[tt][n], bh, a, 0, 0, 0);
          a = __builtin_amdgcn_mfma_f32_16x16x32_bf16(ch[tt][n], bl, a, 0, 0, 0);
          a = __builtin_amdgcn_mfma_f32_16x16x32_bf16(ch[tt][n], bh, a, 0, 0, 0);
          acc[q][tt][n] = a;
        }
    }
    #pragma unroll
    for (int q = 0; q < 4; ++q) {
      const int x = (w * 32 + c * 4 + q) * 16 + m15;
      #pragma unroll
      for (int tt = 0; tt < 2; ++tt) {
        float* __restrict__ up = u + (size_t)(t0 + tt) * EDIM + x;
        const float uval = *up;
        float o = 0.f;
        #pragma unroll
        for (int n = 0; n < 2; ++n) {
          float s;
          s = acc[q][tt][n][0] + uval * pwv[n].x + pbv[n].x;  o += gelu_fast(s) * fv[n].x;
          s = acc[q][tt][n][1] + uval * pwv[n].y + pbv[n].y;  o += gelu_fast(s) * fv[n].y;
          s = acc[q][tt][n][2] + uval * pwv[n].z + pbv[n].z;  o += gelu_fast(s) * fv[n].z;
          s = acc[q][tt][n][3] + uval * pwv[n].w + pbv[n].w;  o += gelu_fast(s) * fv[n].w;
        }
        o += __shfl_xor(o, 16, 64);
        o += __shfl_xor(o, 32, 64);
        if (lane < 16) *up = o + fb;
      }
    }
  }
}

extern "C" void kernel_launch(void* const* d_in, const int* in_sizes, int n_in,
                              void* d_out, int out_size, void* d_ws, size_t ws_size,
                              hipStream_t stream)
{
  const float* x    = (const float*)d_in[0];
  const float* W_en = (const float*)d_in[1];
  const float* b_en = (const float*)d_in[2];
  const float* fc0w = (const float*)d_in[3];
  const float* fc0b = (const float*)d_in[4];
  const float* swr  = (const float*)d_in[5];
  const float* swi  = (const float*)d_in[6];
  const float* pww  = (const float*)d_in[7];
  const float* pwb  = (const float*)d_in[8];
  const float* f1w  = (const float*)d_in[9];
  const float* f1b  = (const float*)d_in[10];
  const float* W_de = (const float*)d_in[11];
  const float* b_de = (const float*)d_in[12];
  float* out = (float*)d_out;
  float* ws  = (float*)d_ws;

  float* u    = ws;                                   // 1024*2048
  float* ctab = u + (size_t)T_ROWS * EDIM;            // 2048
  float* stab = ctab + EDIM;                          // 2048
  float* Wmr  = stab + EDIM;                          // 4*16*32
  float* Wmi  = Wmr + NLAYERS * NMODES * 32;          // 4*16*32
  float* b0r  = Wmi + NLAYERS * NMODES * 32;          // 4*32
  float* pw1  = b0r + NLAYERS * 32;                   // 4*32
  float* pb1  = pw1 + NLAYERS * 32;                   // 4*32
  unsigned short* basFh  = (unsigned short*)(pb1 + NLAYERS * 32);   // 128*64*8
  unsigned short* basFl  = basFh + 128 * 64 * 8;                    // 128*64*8
  unsigned short* coefFh = basFl + 128 * 64 * 8;                    // 1024*2*64*8
  unsigned short* coefFl = coefFh + (size_t)T_ROWS * 2 * 64 * 8;
  unsigned short* WenT   = coefFl + (size_t)T_ROWS * 2 * 64 * 8;    // [2048][1024]
  unsigned short* WdeT   = WenT + (size_t)EDIM * IN_DIM;            // [1024][2048]

  setup_all<<<265, 256, 0, stream>>>(ctab, stab, basFh, basFl, fc0w, fc0b,
                                     swr, swi, pww, pwb, Wmr, Wmi, b0r, pw1, pb1);

  { dim3 g(EDIM / 32, IN_DIM / 32);
    transpose_cvt<<<g, 256, 0, stream>>>(W_en, WenT, IN_DIM, EDIM); }
  { dim3 g(OUT_DIM / 32, EDIM / 32);
    transpose_cvt<<<g, 256, 0, stream>>>(W_de, WdeT, EDIM, OUT_DIM); }

  { dim3 g(EDIM / 64, T_ROWS / 64);
    gemm_mfma<<<g, 256, 0, stream>>>(x, WenT, b_en, u, T_ROWS, EDIM, IN_DIM); }

  for (int l = 0; l < NLAYERS; ++l) {
    dft_coef<<<T_ROWS, 256, 0, stream>>>(u, ctab, stab,
        Wmr + l * NMODES * 32, Wmi + l * NMODES * 32, b0r + l * 32,
        coefFh, coefFl);
    recon_mfma<<<T_ROWS / 2, 256, 0, stream>>>(u, basFh, basFl, coefFh, coefFl,
        pw1 + l * 32, pb1 + l * 32, f1w + l * 32, f1b + l);
  }

  { dim3 g(OUT_DIM / 64, T_ROWS / 64);
    gemm_mfma<<<g, 256, 0, stream>>>(u, WdeT, b_de, out, T_ROWS, OUT_DIM, EDIM); }
}

// Round 6
// 307.032 us; speedup vs baseline: 1.1264x; 1.1264x over previous
//
#include <hip/hip_runtime.h>
#include <math.h>

#ifndef M_PI
#define M_PI 3.14159265358979323846
#endif

#define T_ROWS 1024
#define EDIM   2048
#define IN_DIM 1024
#define OUT_DIM 1024
#define NMODES 16
#define NLAYERS 4

typedef __attribute__((ext_vector_type(8))) short bf16x8;
typedef __attribute__((ext_vector_type(4))) float f32x4;

__device__ __forceinline__ unsigned short f2bf(float f) {
  union { float f; unsigned u; } v; v.f = f;
  unsigned r = v.u + 0x7FFFu + ((v.u >> 16) & 1u);  // RNE
  return (unsigned short)(r >> 16);
}
__device__ __forceinline__ float bf2f(unsigned short h) {
  union { unsigned u; float f; } v; v.u = ((unsigned)h) << 16;
  return v.f;
}
__device__ __forceinline__ void f2bf_split(float v, unsigned short& h, unsigned short& l) {
  h = f2bf(v);
  l = f2bf(v - bf2f(h));
}

__device__ __forceinline__ float gelu_fast(float x) {
  float x2 = x * x;
  float inner = x * (0.7978845608028654f + 0.0356774081f * x2);
  float e2 = __builtin_amdgcn_exp2f(inner * 2.885390081777927f);
  float r  = __builtin_amdgcn_rcpf(e2 + 1.0f);
  return 0.5f * x * (2.0f - 2.0f * r);
}

// Fused setup.
// blocks 0..7: ctab/stab; 8..263: basF hi/lo fragment table [128 mt][64 lane][8 i]
//   x = mt*16 + (lane&15), j = (lane>>4)*8 + i; j<16: cos(2pi j x/2048),
//   16<=j<31: sin(2pi (j-15) x/2048), j==31: 0
// block 264: folded layer weights
__global__ __launch_bounds__(256)
void setup_all(float* __restrict__ ctab, float* __restrict__ stab,
               unsigned short* __restrict__ basFh, unsigned short* __restrict__ basFl,
               const float* __restrict__ fc0w, const float* __restrict__ fc0b,
               const float* __restrict__ wr, const float* __restrict__ wi,
               const float* __restrict__ pww, const float* __restrict__ pwb,
               float* __restrict__ Wmr, float* __restrict__ Wmi,
               float* __restrict__ b0r, float* __restrict__ pw1,
               float* __restrict__ pb1)
{
  const int b = blockIdx.x, tid = threadIdx.x;
  if (b < 8) {
    int i = b * 256 + tid;
    double ang = (2.0 * M_PI / (double)EDIM) * (double)i;
    ctab[i] = (float)cos(ang);
    stab[i] = (float)sin(ang);
  } else if (b < 264) {
    int idx = (b - 8) * 256 + tid;            // [0, 65536)
    int mt = idx >> 9;
    int l  = (idx >> 3) & 63;
    int i  = idx & 7;
    int x  = mt * 16 + (l & 15);
    int j  = (l >> 4) * 8 + i;
    float v = 0.0f;
    if (j < 31) {
      int m = (j < NMODES) ? j : (j - 15);
      int ia = (m * x) & (EDIM - 1);
      double ang = (2.0 * M_PI / (double)EDIM) * (double)ia;
      v = (j < NMODES) ? (float)cos(ang) : (float)sin(ang);
    }
    unsigned short h, lo; f2bf_split(v, h, lo);
    basFh[idx] = h; basFl[idx] = lo;
  } else {
    if (tid >= NLAYERS * 32) return;
    int l = tid >> 5, d = tid & 31;
    for (int m = 0; m < NMODES; ++m) {
      float sr = 0.f, si = 0.f;
      for (int c = 0; c < 32; ++c) {
        float w0 = fc0w[l * 32 + c];
        size_t base = ((size_t)(l * 32 + c) * 32 + d) * NMODES + m;
        sr += w0 * wr[base];
        si += w0 * wi[base];
      }
      Wmr[(l * NMODES + m) * 32 + d] = sr;
      Wmi[(l * NMODES + m) * 32 + d] = si;
    }
    float sb = 0.f, sp = 0.f, sq = 0.f;
    for (int c = 0; c < 32; ++c) {
      float b0 = fc0b[l * 32 + c];
      float w0 = fc0w[l * 32 + c];
      sb += b0 * wr[((size_t)(l * 32 + c) * 32 + d) * NMODES + 0];
      float pw = pww[(size_t)(l * 32 + c) * 32 + d];
      sp += w0 * pw;
      sq += b0 * pw;
    }
    b0r[l * 32 + d] = (float)EDIM * sb;
    pw1[l * 32 + d] = sp;
    pb1[l * 32 + d] = sq + pwb[l * 32 + d];
  }
}

// B[K][N] fp32 -> BT[N][K] bf16, 32x32 tiles
__global__ __launch_bounds__(256)
void transpose_cvt(const float* __restrict__ B, unsigned short* __restrict__ BT,
                   int K, int N)
{
  __shared__ float tile[32][33];
  const int k0 = blockIdx.y * 32, n0 = blockIdx.x * 32;
  const int tid = threadIdx.x;
  {
    int r = tid >> 3, c4 = (tid & 7) * 4;
    float4 v = *(const float4*)&B[(size_t)(k0 + r) * N + n0 + c4];
    tile[r][c4 + 0] = v.x; tile[r][c4 + 1] = v.y;
    tile[r][c4 + 2] = v.z; tile[r][c4 + 3] = v.w;
  }
  __syncthreads();
  {
    int n = tid >> 3, kq = (tid & 7) * 4;
    ushort4 o;
    o.x = f2bf(tile[kq + 0][n]); o.y = f2bf(tile[kq + 1][n]);
    o.z = f2bf(tile[kq + 2][n]); o.w = f2bf(tile[kq + 3][n]);
    *(ushort4*)&BT[(size_t)(n0 + n) * K + k0 + kq] = o;
  }
}

// C[M][N] = A[M][K](fp32 -> bf16 on stage) @ BT[N][K]^T + bias. 64x64 tile, BK=64.
#define BKK 64
__global__ __launch_bounds__(256)
void gemm_mfma(const float* __restrict__ A, const unsigned short* __restrict__ BT,
               const float* __restrict__ bias, float* __restrict__ C,
               int M, int N, int K)
{
  __shared__ __align__(16) unsigned short Asb[64 * BKK];
  __shared__ __align__(16) unsigned short Bsb[64 * BKK];
  const int tid = threadIdx.x;
  const int bm = blockIdx.y * 64, bn = blockIdx.x * 64;
  const int lane = tid & 63, wave = tid >> 6;
  const int wr = wave >> 1, wc = wave & 1;

  const int srow = tid >> 2;          // 0..63
  const int skq  = tid & 3;           // 16-k chunk

  f32x4 acc[2][2] = {};

  const float* aRow = A + (size_t)(bm + srow) * K + skq * 16;
  const unsigned short* bRow = BT + (size_t)(bn + srow) * K + skq * 16;

  for (int k0 = 0; k0 < K; k0 += BKK) {
    #pragma unroll
    for (int h = 0; h < 2; ++h) {
      int kb = skq * 2 + h;
      int slot = kb ^ ((srow >> 1) & 7);
      {
        float4 a0 = *(const float4*)(aRow + k0 + h * 8);
        float4 a1 = *(const float4*)(aRow + k0 + h * 8 + 4);
        union { unsigned short u[8]; bf16x8 v; } pk;
        pk.u[0] = f2bf(a0.x); pk.u[1] = f2bf(a0.y); pk.u[2] = f2bf(a0.z); pk.u[3] = f2bf(a0.w);
        pk.u[4] = f2bf(a1.x); pk.u[5] = f2bf(a1.y); pk.u[6] = f2bf(a1.z); pk.u[7] = f2bf(a1.w);
        *(bf16x8*)&Asb[srow * BKK + slot * 8] = pk.v;
      }
      *(bf16x8*)&Bsb[srow * BKK + slot * 8] = *(const bf16x8*)(bRow + k0 + h * 8);
    }
    __syncthreads();
    #pragma unroll
    for (int s = 0; s < 2; ++s) {
      int kb = s * 4 + (lane >> 4);
      bf16x8 a[2], b[2];
      #pragma unroll
      for (int i = 0; i < 2; ++i) {
        int ar = wr * 32 + i * 16 + (lane & 15);
        a[i] = *(const bf16x8*)&Asb[ar * BKK + (kb ^ ((ar >> 1) & 7)) * 8];
        int br = wc * 32 + i * 16 + (lane & 15);
        b[i] = *(const bf16x8*)&Bsb[br * BKK + (kb ^ ((br >> 1) & 7)) * 8];
      }
      #pragma unroll
      for (int i = 0; i < 2; ++i)
        #pragma unroll
        for (int j = 0; j < 2; ++j)
          acc[i][j] = __builtin_amdgcn_mfma_f32_16x16x32_bf16(a[i], b[j], acc[i][j], 0, 0, 0);
    }
    __syncthreads();
  }

  #pragma unroll
  for (int j = 0; j < 2; ++j) {
    int col = bn + wc * 32 + j * 16 + (lane & 15);
    float bz = bias[col];
    #pragma unroll
    for (int i = 0; i < 2; ++i)
      #pragma unroll
      for (int r = 0; r < 4; ++r) {
        int row = bm + wr * 32 + i * 16 + (lane >> 4) * 4 + r;
        C[(size_t)row * N + col] = acc[i][j][r] + bz;
      }
  }
}

// 16-mode DFT per row + mode mix -> bf16 hi/lo fragments coefF[t][n][lane][8]
__global__ __launch_bounds__(256)
void dft_coef(const float* __restrict__ u,
              const float* __restrict__ ctab, const float* __restrict__ stab,
              const float* __restrict__ Wmr, const float* __restrict__ Wmi,
              const float* __restrict__ b0r,
              unsigned short* __restrict__ coefFh, unsigned short* __restrict__ coefFl)
{
  const int t = blockIdx.x, tid = threadIdx.x;
  __shared__ float lc[EDIM + 64], ls[EDIM + 64];
  __shared__ float red[4][32];
  __shared__ float Ush[32];

  for (int i = tid; i < EDIM; i += 256) {
    int p = i + (i >> 5);
    lc[p] = ctab[i];
    ls[p] = stab[i];
  }
  float ur[8];
  #pragma unroll
  for (int it = 0; it < 8; ++it) ur[it] = u[(size_t)t * EDIM + tid + it * 256];
  __syncthreads();

  float pr[NMODES], pi[NMODES];
  #pragma unroll
  for (int m = 0; m < NMODES; ++m) { pr[m] = 0.f; pi[m] = 0.f; }
  #pragma unroll
  for (int it = 0; it < 8; ++it) {
    int x = tid + it * 256;
    float val = ur[it];
    #pragma unroll
    for (int m = 0; m < NMODES; ++m) {
      int idx = (m * x) & (EDIM - 1);
      int p = idx + (idx >> 5);
      pr[m] += val * lc[p];
      pi[m] -= val * ls[p];
    }
  }
  #pragma unroll
  for (int m = 0; m < NMODES; ++m) {
    #pragma unroll
    for (int off = 32; off > 0; off >>= 1) {
      pr[m] += __shfl_down(pr[m], off, 64);
      pi[m] += __shfl_down(pi[m], off, 64);
    }
  }
  int lane = tid & 63, wid = tid >> 6;
  if (lane == 0) {
    #pragma unroll
    for (int m = 0; m < NMODES; ++m) { red[wid][m] = pr[m]; red[wid][NMODES + m] = pi[m]; }
  }
  __syncthreads();
  if (tid < 32) Ush[tid] = red[0][tid] + red[1][tid] + red[2][tid] + red[3][tid];
  __syncthreads();

  if (tid < 128) {
    const float invN = 1.0f / (float)EDIM;
    int n = tid >> 6, l = tid & 63;
    int d = n * 16 + (l & 15);
    union { unsigned short u[8]; bf16x8 v; } ph, pl;
    #pragma unroll
    for (int i = 0; i < 8; ++i) {
      int j = (l >> 4) * 8 + i;
      float v = 0.f;
      if (j < 31) {
        if (j < NMODES) {
          int m = j;
          float ofr = Ush[m] * Wmr[m * 32 + d] - Ush[NMODES + m] * Wmi[m * 32 + d];
          v = (m == 0) ? (ofr + b0r[d]) * invN : 2.0f * ofr * invN;
        } else {
          int m = j - 15;
          float ofi = Ush[m] * Wmi[m * 32 + d] + Ush[NMODES + m] * Wmr[m * 32 + d];
          v = -2.0f * ofi * invN;
        }
      }
      f2bf_split(v, ph.u[i], pl.u[i]);
    }
    size_t base = ((size_t)t * 2 + n) * 64 + l;
    *(bf16x8*)&coefFh[base * 8] = ph.v;
    *(bf16x8*)&coefFl[base * 8] = pl.v;
  }
}

// MFMA reconstruction + gelu + fc1, in-place on u.
// Grid = 4*T_ROWS: block = (t, cq) covers x in [cq*512, cq*512+512).
// Operand-swapped mfma(coef, bas): lane holds (d-slice, x=m15); epilogue in
// registers, fc1 reduce = 2 shfl_xor. Per-q epilogue keeps acc live-range small.
__global__ __launch_bounds__(256, 6)
void recon_mfma(float* __restrict__ u,
                const unsigned short* __restrict__ basFh,
                const unsigned short* __restrict__ basFl,
                const unsigned short* __restrict__ coefFh,
                const unsigned short* __restrict__ coefFl,
                const float* __restrict__ pw1, const float* __restrict__ pb1,
                const float* __restrict__ f1w, const float* __restrict__ f1b)
{
  const int t  = blockIdx.x >> 2;
  const int cq = blockIdx.x & 3;
  const int tid = threadIdx.x, lane = tid & 63, w = tid >> 6;
  const int g = lane >> 4, m15 = lane & 15;

  bf16x8 ch[2], cl[2];
  #pragma unroll
  for (int n = 0; n < 2; ++n) {
    size_t base = (((size_t)t * 2 + n) * 64 + lane) * 8;
    ch[n] = *(const bf16x8*)&coefFh[base];
    cl[n] = *(const bf16x8*)&coefFl[base];
  }

  float4 pwv[2], pbv[2], fv[2];
  #pragma unroll
  for (int n = 0; n < 2; ++n) {
    pwv[n] = *(const float4*)&pw1[n * 16 + g * 4];
    pbv[n] = *(const float4*)&pb1[n * 16 + g * 4];
    fv[n]  = *(const float4*)&f1w[n * 16 + g * 4];
  }
  const float fb = f1b[0];
  float* __restrict__ urow = u + (size_t)t * EDIM;

  #pragma unroll
  for (int c2 = 0; c2 < 2; ++c2) {
    #pragma unroll
    for (int q = 0; q < 4; ++q) {
      const int mt = cq * 32 + w * 8 + c2 * 4 + q;
      bf16x8 bh = *(const bf16x8*)&basFh[((size_t)mt * 64 + lane) * 8];
      bf16x8 bl = *(const bf16x8*)&basFl[((size_t)mt * 64 + lane) * 8];
      f32x4 acc[2];
      #pragma unroll
      for (int n = 0; n < 2; ++n) {
        f32x4 a = {};
        a = __builtin_amdgcn_mfma_f32_16x16x32_bf16(cl[n], bh, a, 0, 0, 0);
        a = __builtin_amdgcn_mfma_f32_16x16x32_bf16(ch[n], bl, a, 0, 0, 0);
        a = __builtin_amdgcn_mfma_f32_16x16x32_bf16(ch[n], bh, a, 0, 0, 0);
        acc[n] = a;
      }
      const int x = mt * 16 + m15;
      float* __restrict__ up = urow + x;
      const float uval = *up;
      float o = 0.f;
      #pragma unroll
      for (int n = 0; n < 2; ++n) {
        float s;
        s = acc[n][0] + uval * pwv[n].x + pbv[n].x;  o += gelu_fast(s) * fv[n].x;
        s = acc[n][1] + uval * pwv[n].y + pbv[n].y;  o += gelu_fast(s) * fv[n].y;
        s = acc[n][2] + uval * pwv[n].z + pbv[n].z;  o += gelu_fast(s) * fv[n].z;
        s = acc[n][3] + uval * pwv[n].w + pbv[n].w;  o += gelu_fast(s) * fv[n].w;
      }
      o += __shfl_xor(o, 16, 64);
      o += __shfl_xor(o, 32, 64);
      if (lane < 16) *up = o + fb;
    }
  }
}

extern "C" void kernel_launch(void* const* d_in, const int* in_sizes, int n_in,
                              void* d_out, int out_size, void* d_ws, size_t ws_size,
                              hipStream_t stream)
{
  const float* x    = (const float*)d_in[0];
  const float* W_en = (const float*)d_in[1];
  const float* b_en = (const float*)d_in[2];
  const float* fc0w = (const float*)d_in[3];
  const float* fc0b = (const float*)d_in[4];
  const float* swr  = (const float*)d_in[5];
  const float* swi  = (const float*)d_in[6];
  const float* pww  = (const float*)d_in[7];
  const float* pwb  = (const float*)d_in[8];
  const float* f1w  = (const float*)d_in[9];
  const float* f1b  = (const float*)d_in[10];
  const float* W_de = (const float*)d_in[11];
  const float* b_de = (const float*)d_in[12];
  float* out = (float*)d_out;
  float* ws  = (float*)d_ws;

  float* u    = ws;                                   // 1024*2048
  float* ctab = u + (size_t)T_ROWS * EDIM;            // 2048
  float* stab = ctab + EDIM;                          // 2048
  float* Wmr  = stab + EDIM;                          // 4*16*32
  float* Wmi  = Wmr + NLAYERS * NMODES * 32;          // 4*16*32
  float* b0r  = Wmi + NLAYERS * NMODES * 32;          // 4*32
  float* pw1  = b0r + NLAYERS * 32;                   // 4*32
  float* pb1  = pw1 + NLAYERS * 32;                   // 4*32
  unsigned short* basFh  = (unsigned short*)(pb1 + NLAYERS * 32);   // 128*64*8
  unsigned short* basFl  = basFh + 128 * 64 * 8;                    // 128*64*8
  unsigned short* coefFh = basFl + 128 * 64 * 8;                    // 1024*2*64*8
  unsigned short* coefFl = coefFh + (size_t)T_ROWS * 2 * 64 * 8;
  unsigned short* WenT   = coefFl + (size_t)T_ROWS * 2 * 64 * 8;    // [2048][1024]
  unsigned short* WdeT   = WenT + (size_t)EDIM * IN_DIM;            // [1024][2048]

  setup_all<<<265, 256, 0, stream>>>(ctab, stab, basFh, basFl, fc0w, fc0b,
                                     swr, swi, pww, pwb, Wmr, Wmi, b0r, pw1, pb1);

  { dim3 g(EDIM / 32, IN_DIM / 32);
    transpose_cvt<<<g, 256, 0, stream>>>(W_en, WenT, IN_DIM, EDIM); }
  { dim3 g(OUT_DIM / 32, EDIM / 32);
    transpose_cvt<<<g, 256, 0, stream>>>(W_de, WdeT, EDIM, OUT_DIM); }

  { dim3 g(EDIM / 64, T_ROWS / 64);
    gemm_mfma<<<g, 256, 0, stream>>>(x, WenT, b_en, u, T_ROWS, EDIM, IN_DIM); }

  for (int l = 0; l < NLAYERS; ++l) {
    dft_coef<<<T_ROWS, 256, 0, stream>>>(u, ctab, stab,
        Wmr + l * NMODES * 32, Wmi + l * NMODES * 32, b0r + l * 32,
        coefFh, coefFl);
    recon_mfma<<<4 * T_ROWS, 256, 0, stream>>>(u, basFh, basFl, coefFh, coefFl,
        pw1 + l * 32, pb1 + l * 32, f1w + l * 32, f1b + l);
  }

  { dim3 g(OUT_DIM / 64, T_ROWS / 64);
    gemm_mfma<<<g, 256, 0, stream>>>(u, WdeT, b_de, out, T_ROWS, OUT_DIM, EDIM); }
}